// Round 1
// baseline (799.011 us; speedup 1.0000x reference)
//
#include <hip/hip_runtime.h>
#include <hip/hip_bf16.h>

#define IN_DIM 128

typedef __hip_bfloat16 bf16;

// ---------------- CSR build (once per launch; graph is static) ----------------

__global__ void k_count(const int* __restrict__ dst, int* __restrict__ deg, int E) {
  int i = blockIdx.x * 256 + threadIdx.x;
  if (i < E) atomicAdd(&deg[dst[i]], 1);
}

__global__ __launch_bounds__(1024) void k_scan(const int* __restrict__ deg,
                                               int* __restrict__ row_start,
                                               int* __restrict__ cursor, int n) {
  __shared__ int part[1024];
  int tid = threadIdx.x;
  int per = (n + 1023) >> 10;
  int lo = tid * per, hi = min(lo + per, n);
  int s = 0;
  for (int i = lo; i < hi; ++i) s += deg[i];
  part[tid] = s;
  __syncthreads();
  for (int d = 1; d < 1024; d <<= 1) {
    int v = (tid >= d) ? part[tid - d] : 0;
    __syncthreads();
    if (tid >= d) part[tid] += v;
    __syncthreads();
  }
  int run = (tid == 0) ? 0 : part[tid - 1];
  for (int i = lo; i < hi; ++i) {
    row_start[i] = run; cursor[i] = run; run += deg[i];
  }
  if (tid == 1023) row_start[n] = run;
}

__global__ void k_fill(const int* __restrict__ src, const int* __restrict__ dst,
                       const int* __restrict__ et, int* __restrict__ cursor,
                       int* __restrict__ packed, int E) {
  int i = blockIdx.x * 256 + threadIdx.x;
  if (i < E) {
    int d = dst[i];
    int pos = atomicAdd(&cursor[d], 1);
    packed[pos] = src[i] | (et[i] << 16);   // src < 50000 < 2^16
  }
}

// Build Wcat[l][128][256] = [A0|A1|B0|B1] columns; bcat holds b1 folded into B cols.
__global__ void k_prep(const float* __restrict__ eW1, const float* __restrict__ eb1,
                       float* __restrict__ Wcat, float* __restrict__ bcat) {
  int idx = blockIdx.x * 256 + threadIdx.x;
  if (idx < 3 * 128 * 256) {
    int l = idx / (128 * 256);
    int r = idx % (128 * 256);
    int k = r / 256, c = r % 256;
    int e = (c >> 6) & 1;
    int row = (c < 128) ? k : (128 + k);
    Wcat[idx] = eW1[((l * 2 + e) * 256 + row) * 64 + (c & 63)];
  }
  if (idx < 3 * 256) {
    int l = idx >> 8, c = idx & 255;
    float b = 0.f;
    if (c >= 128) {
      int e = (c >> 6) & 1;
      b = eb1[(l * 2 + e) * 64 + (c & 63)];
    }
    bcat[idx] = b;
  }
}

// ---------------- generic fp32 tiled GEMM: out = [relu](A @ W + bias) ----------------
// A: [M,K] (SPLIT_A: cols 0..63 from A (width 64), 64..K-1 from A2 (width 128))
// W: [K,NCOL] row-major. out: [M,NCOL] fp32 or bf16.

template <int K, int NCOL, bool RELU, bool OUT_BF16, bool SPLIT_A>
__global__ __launch_bounds__(256) void k_gemm(const float* __restrict__ A,
                                              const float* __restrict__ A2,
                                              const float* __restrict__ W,
                                              const float* __restrict__ bias,
                                              void* __restrict__ out, int M) {
  constexpr int BM = 64, BN = 64, BK = 32;
  __shared__ float lds_a[BK][BM];
  __shared__ float lds_w[BK][BN];
  int t = threadIdx.x;
  int tx = t & 15, ty = t >> 4;
  int m0 = blockIdx.x * BM;
  int n0 = blockIdx.y * BN;
  float acc[4][4] = {};
  for (int kc = 0; kc < K; kc += BK) {
#pragma unroll
    for (int it = 0; it < 2; ++it) {        // A tile: 64 rows x 32 k = 512 float4
      int idx = t + it * 256;
      int row = idx >> 3, f4 = idx & 7;
      int gr = m0 + row; if (gr >= M) gr = M - 1;
      int k = kc + f4 * 4;
      float4 v;
      if (SPLIT_A) {
        if (k < 64) v = *reinterpret_cast<const float4*>(&A[(long)gr * 64 + k]);
        else        v = *reinterpret_cast<const float4*>(&A2[(long)gr * 128 + (k - 64)]);
      } else {
        v = *reinterpret_cast<const float4*>(&A[(long)gr * K + k]);
      }
      lds_a[f4 * 4 + 0][row] = v.x;
      lds_a[f4 * 4 + 1][row] = v.y;
      lds_a[f4 * 4 + 2][row] = v.z;
      lds_a[f4 * 4 + 3][row] = v.w;
    }
#pragma unroll
    for (int it = 0; it < 2; ++it) {        // W tile: 32 k x 64 cols
      int idx = t + it * 256;
      int kk = idx >> 4, c4 = idx & 15;
      float4 v = *reinterpret_cast<const float4*>(&W[(long)(kc + kk) * NCOL + n0 + c4 * 4]);
      *reinterpret_cast<float4*>(&lds_w[kk][c4 * 4]) = v;
    }
    __syncthreads();
#pragma unroll
    for (int k = 0; k < BK; ++k) {
      float4 a4 = *reinterpret_cast<const float4*>(&lds_a[k][ty * 4]);
      float4 w4 = *reinterpret_cast<const float4*>(&lds_w[k][tx * 4]);
      float aa[4] = {a4.x, a4.y, a4.z, a4.w};
      float ww[4] = {w4.x, w4.y, w4.z, w4.w};
#pragma unroll
      for (int i = 0; i < 4; ++i)
#pragma unroll
        for (int j = 0; j < 4; ++j) acc[i][j] = fmaf(aa[i], ww[j], acc[i][j]);
    }
    __syncthreads();
  }
#pragma unroll
  for (int i = 0; i < 4; ++i) {
    int gr = m0 + ty * 4 + i;
    if (gr >= M) continue;
#pragma unroll
    for (int j = 0; j < 4; ++j) {
      int gc = n0 + tx * 4 + j;
      float v = acc[i][j] + bias[gc];
      if (RELU) v = fmaxf(v, 0.f);
      if (OUT_BF16) ((bf16*)out)[(long)gr * NCOL + gc] = __float2bfloat16(v);
      else          ((float*)out)[(long)gr * NCOL + gc] = v;
    }
  }
}

// ---------------- edge phase: per-dst-node accumulate relu(A_e[src]+B_e[dst]), then @W2 ----
// P layout per node: [A0(64) | A1(64) | B0+b1(64) | B1+b1(64)] bf16.
// msg[n][0:32]=mean msg etype0, [32:64]=etype1 (matches concat order for node MLP).

__global__ __launch_bounds__(256) void k_edge(const bf16* __restrict__ P,
                                              const int* __restrict__ row_start,
                                              const int* __restrict__ packed,
                                              const float* __restrict__ W2,  // [2][64][32]
                                              const float* __restrict__ b2,  // [2][32]
                                              float* __restrict__ msg, int n) {
  __shared__ float s_w2[2 * 64 * 32];
  __shared__ float s_b2[64];
  __shared__ float s_acc[4][2][64];
  int t = threadIdx.x;
  for (int i = t; i < 4096; i += 256) s_w2[i] = W2[i];
  if (t < 64) s_b2[t] = b2[t];
  int w = t >> 6, lane = t & 63;
  int node = blockIdx.x * 4 + w;
  float acc0 = 0.f, acc1 = 0.f;
  int cnt1 = 0, total = 0;
  if (node < n) {
    const bf16* Pb = P + (long)node * 256 + 128;
    float b0v = __bfloat162float(Pb[lane]);
    float b1v = __bfloat162float(Pb[64 + lane]);
    int beg = row_start[node], end = row_start[node + 1];
    total = end - beg;
    for (int p = beg; p < end; ++p) {
      int pk = packed[p];                 // wave-uniform broadcast load
      int s = pk & 0xFFFF;
      int e = pk >> 16;
      float a = __bfloat162float(P[(long)s * 256 + (e << 6) + lane]);
      float hv = fmaxf(a + (e ? b1v : b0v), 0.f);
      if (e) acc1 += hv; else acc0 += hv;
      cnt1 += e;
    }
  }
  int cnt0 = total - cnt1;
  float sc0 = cnt0 > 0 ? 1.f / (float)cnt0 : 0.f;
  float sc1 = cnt1 > 0 ? 1.f / (float)cnt1 : 0.f;
  s_acc[w][0][lane] = acc0 * sc0;
  s_acc[w][1][lane] = acc1 * sc1;
  __syncthreads();
  if (node < n) {
    int e = lane >> 5, c = lane & 31;
    int cnte = e ? cnt1 : cnt0;
    float outv = cnte > 0 ? s_b2[e * 32 + c] : 0.f;  // b2 only when node has etype-e edges
    float sum = 0.f;
#pragma unroll 8
    for (int j = 0; j < 64; ++j)
      sum = fmaf(s_acc[w][e][j], s_w2[(e * 64 + j) * 32 + c], sum);
    msg[(long)node * 64 + lane] = outv + sum;
  }
}

// ---------------- launch ----------------

extern "C" void kernel_launch(void* const* d_in, const int* in_sizes, int n_in,
                              void* d_out, int out_size, void* d_ws, size_t ws_size,
                              hipStream_t stream) {
  const float* nf  = (const float*)d_in[0];
  const float* eW1 = (const float*)d_in[1];
  const float* eb1 = (const float*)d_in[2];
  const float* eW2 = (const float*)d_in[3];
  const float* eb2 = (const float*)d_in[4];
  const float* nW1 = (const float*)d_in[5];
  const float* nb1 = (const float*)d_in[6];
  const float* nW2 = (const float*)d_in[7];
  const float* nb2 = (const float*)d_in[8];
  const int* src = (const int*)d_in[9];
  const int* dst = (const int*)d_in[10];
  const int* et  = (const int*)d_in[11];
  const int N = in_sizes[0] / IN_DIM;
  const int E = in_sizes[9];

  char* wp = (char*)d_ws;
  auto alloc = [&](size_t bytes) {
    char* p = wp; wp += (bytes + 255) & ~(size_t)255; return p;
  };
  int*   deg       = (int*)alloc((size_t)N * 4);
  int*   row_start = (int*)alloc((size_t)(N + 1) * 4);
  int*   cursor    = (int*)alloc((size_t)N * 4);
  int*   packed    = (int*)alloc((size_t)E * 4);
  float* Wcat      = (float*)alloc((size_t)3 * 128 * 256 * 4);
  float* bcat      = (float*)alloc((size_t)3 * 256 * 4);
  bf16*  P         = (bf16*)alloc((size_t)N * 256 * 2);
  float* msg       = (float*)alloc((size_t)N * 64 * 4);
  float* U         = (float*)alloc((size_t)N * 64 * 4);
  float* hbuf      = (float*)alloc((size_t)N * 128 * 4);

  hipMemsetAsync(deg, 0, (size_t)N * 4, stream);
  k_count<<<(E + 255) / 256, 256, 0, stream>>>(dst, deg, E);
  k_scan<<<1, 1024, 0, stream>>>(deg, row_start, cursor, N);
  k_fill<<<(E + 255) / 256, 256, 0, stream>>>(src, dst, et, cursor, packed, E);
  k_prep<<<(3 * 128 * 256 + 255) / 256, 256, 0, stream>>>(eW1, eb1, Wcat, bcat);

  int gm = (N + 63) / 64;
  const float* h = nf;
  for (int l = 0; l < 3; ++l) {
    // P = h @ Wcat[l] + bcat[l]  -> bf16 [N,256]
    k_gemm<128, 256, false, true, false><<<dim3(gm, 4), 256, 0, stream>>>(
        h, nullptr, Wcat + l * 128 * 256, bcat + l * 256, P, N);
    // per-node message accumulation + mean + @W2 + b2
    k_edge<<<(N + 3) / 4, 256, 0, stream>>>(
        P, row_start, packed, eW2 + l * 2 * 64 * 32, eb2 + l * 2 * 32, msg, N);
    // U = relu([msg | h] @ nW1[l] + nb1[l])
    k_gemm<192, 64, true, false, true><<<dim3(gm, 1), 256, 0, stream>>>(
        msg, h, nW1 + l * 192 * 64, nb1 + l * 64, U, N);
    // h' = U @ nW2[l] + nb2[l]
    float* hout = (l == 2) ? (float*)d_out : hbuf;
    k_gemm<64, 128, false, false, false><<<dim3(gm, 2), 256, 0, stream>>>(
        U, nullptr, nW2 + l * 64 * 128, nb2 + l * 128, hout, N);
    h = hbuf;
  }
}

// Round 2
// 521.112 us; speedup vs baseline: 1.5333x; 1.5333x over previous
//
#include <hip/hip_runtime.h>
#include <hip/hip_bf16.h>

#define IN_DIM 128

typedef __hip_bfloat16 bf16;

// ---------------- CSR build (etype-split: segment index = 2*dst + etype) ----------------

__global__ void k_count(const int* __restrict__ dst, const int* __restrict__ et,
                        int* __restrict__ deg, int E) {
  int i = blockIdx.x * 256 + threadIdx.x;
  if (i < E) atomicAdd(&deg[2 * dst[i] + et[i]], 1);
}

// Phase A: per-block (1024 elements) local exclusive scan; block sums out.
__global__ __launch_bounds__(256) void k_scanA(const int* __restrict__ deg,
                                               int* __restrict__ tmp,
                                               int* __restrict__ bsum, int M) {
  __shared__ int ts[256];
  int t = threadIdx.x;
  int base = blockIdx.x * 1024 + t * 4;
  int d[4];
#pragma unroll
  for (int i = 0; i < 4; ++i) d[i] = (base + i < M) ? deg[base + i] : 0;
  ts[t] = d[0] + d[1] + d[2] + d[3];
  __syncthreads();
  for (int dd = 1; dd < 256; dd <<= 1) {
    int v = (t >= dd) ? ts[t - dd] : 0;
    __syncthreads();
    ts[t] += v;
    __syncthreads();
  }
  int run = (t == 0) ? 0 : ts[t - 1];
#pragma unroll
  for (int i = 0; i < 4; ++i) {
    if (base + i < M) tmp[base + i] = run;
    run += d[i];
  }
  if (t == 255) bsum[blockIdx.x] = ts[255];
}

// Phase B: exclusive scan of block sums (nb <= 256), single block.
__global__ __launch_bounds__(256) void k_scanB(int* __restrict__ bsum, int nb) {
  __shared__ int s[256];
  int t = threadIdx.x;
  s[t] = (t < nb) ? bsum[t] : 0;
  __syncthreads();
  for (int dd = 1; dd < 256; dd <<= 1) {
    int v = (t >= dd) ? s[t - dd] : 0;
    __syncthreads();
    s[t] += v;
    __syncthreads();
  }
  if (t < nb) bsum[t] = (t == 0) ? 0 : s[t - 1];
}

// Phase C: global prefix = local + block offset; writes row_start and cursor.
__global__ void k_scanC(const int* __restrict__ tmp, const int* __restrict__ bsum,
                        int* __restrict__ row_start, int* __restrict__ cursor,
                        int M, int E) {
  int i = blockIdx.x * 256 + threadIdx.x;
  if (i < M) {
    int v = tmp[i] + bsum[i >> 10];
    row_start[i] = v;
    cursor[i] = v;
  }
  if (i == 0) row_start[M] = E;
}

__global__ void k_fill(const int* __restrict__ src, const int* __restrict__ dst,
                       const int* __restrict__ et, int* __restrict__ cursor,
                       int* __restrict__ packed, int E) {
  int i = blockIdx.x * 256 + threadIdx.x;
  if (i < E) {
    int pos = atomicAdd(&cursor[2 * dst[i] + et[i]], 1);
    packed[pos] = src[i];
  }
}

// Build Wcat[l][128][256] = [A0|A1|B0|B1] columns; bcat holds b1 folded into B cols.
__global__ void k_prep(const float* __restrict__ eW1, const float* __restrict__ eb1,
                       float* __restrict__ Wcat, float* __restrict__ bcat) {
  int idx = blockIdx.x * 256 + threadIdx.x;
  if (idx < 3 * 128 * 256) {
    int l = idx / (128 * 256);
    int r = idx % (128 * 256);
    int k = r / 256, c = r % 256;
    int e = (c >> 6) & 1;
    int row = (c < 128) ? k : (128 + k);
    Wcat[idx] = eW1[((l * 2 + e) * 256 + row) * 64 + (c & 63)];
  }
  if (idx < 3 * 256) {
    int l = idx >> 8, c = idx & 255;
    float b = 0.f;
    if (c >= 128) {
      int e = (c >> 6) & 1;
      b = eb1[(l * 2 + e) * 64 + (c & 63)];
    }
    bcat[idx] = b;
  }
}

// ---------------- generic fp32 tiled GEMM: out = [relu](A @ W + bias) ----------------

template <int K, int NCOL, bool RELU, bool OUT_BF16, bool SPLIT_A>
__global__ __launch_bounds__(256) void k_gemm(const float* __restrict__ A,
                                              const float* __restrict__ A2,
                                              const float* __restrict__ W,
                                              const float* __restrict__ bias,
                                              void* __restrict__ out, int M) {
  constexpr int BM = 64, BN = 64, BK = 32;
  __shared__ float lds_a[BK][BM];
  __shared__ float lds_w[BK][BN];
  int t = threadIdx.x;
  int tx = t & 15, ty = t >> 4;
  int m0 = blockIdx.x * BM;
  int n0 = blockIdx.y * BN;
  float acc[4][4] = {};
  for (int kc = 0; kc < K; kc += BK) {
#pragma unroll
    for (int it = 0; it < 2; ++it) {
      int idx = t + it * 256;
      int row = idx >> 3, f4 = idx & 7;
      int gr = m0 + row; if (gr >= M) gr = M - 1;
      int k = kc + f4 * 4;
      float4 v;
      if (SPLIT_A) {
        if (k < 64) v = *reinterpret_cast<const float4*>(&A[(long)gr * 64 + k]);
        else        v = *reinterpret_cast<const float4*>(&A2[(long)gr * 128 + (k - 64)]);
      } else {
        v = *reinterpret_cast<const float4*>(&A[(long)gr * K + k]);
      }
      lds_a[f4 * 4 + 0][row] = v.x;
      lds_a[f4 * 4 + 1][row] = v.y;
      lds_a[f4 * 4 + 2][row] = v.z;
      lds_a[f4 * 4 + 3][row] = v.w;
    }
#pragma unroll
    for (int it = 0; it < 2; ++it) {
      int idx = t + it * 256;
      int kk = idx >> 4, c4 = idx & 15;
      float4 v = *reinterpret_cast<const float4*>(&W[(long)(kc + kk) * NCOL + n0 + c4 * 4]);
      *reinterpret_cast<float4*>(&lds_w[kk][c4 * 4]) = v;
    }
    __syncthreads();
#pragma unroll
    for (int k = 0; k < BK; ++k) {
      float4 a4 = *reinterpret_cast<const float4*>(&lds_a[k][ty * 4]);
      float4 w4 = *reinterpret_cast<const float4*>(&lds_w[k][tx * 4]);
      float aa[4] = {a4.x, a4.y, a4.z, a4.w};
      float ww[4] = {w4.x, w4.y, w4.z, w4.w};
#pragma unroll
      for (int i = 0; i < 4; ++i)
#pragma unroll
        for (int j = 0; j < 4; ++j) acc[i][j] = fmaf(aa[i], ww[j], acc[i][j]);
    }
    __syncthreads();
  }
#pragma unroll
  for (int i = 0; i < 4; ++i) {
    int gr = m0 + ty * 4 + i;
    if (gr >= M) continue;
#pragma unroll
    for (int j = 0; j < 4; ++j) {
      int gc = n0 + tx * 4 + j;
      float v = acc[i][j] + bias[gc];
      if (RELU) v = fmaxf(v, 0.f);
      if (OUT_BF16) ((bf16*)out)[(long)gr * NCOL + gc] = __float2bfloat16(v);
      else          ((float*)out)[(long)gr * NCOL + gc] = v;
    }
  }
}

// ---------------- edge phase ----------------
// P layout per node: [A0(64) | A1(64) | B0+b1(64) | B1+b1(64)] bf16.
// Per dst node & etype e: mean over edges of relu(A_e[src] + B_e[dst]), then @W2[e] + b2[e].

__device__ __forceinline__ float seg_acc(const bf16* __restrict__ P,
                                         const int* __restrict__ packed,
                                         int beg, int end, int off, int lane,
                                         float bv) {
  float a0 = 0.f, a1 = 0.f, a2 = 0.f, a3 = 0.f;
  int p = beg;
  for (; p + 4 <= end; p += 4) {
    int s0 = packed[p], s1 = packed[p + 1], s2 = packed[p + 2], s3 = packed[p + 3];
    float v0 = __bfloat162float(P[(size_t)s0 * 256 + off + lane]);
    float v1 = __bfloat162float(P[(size_t)s1 * 256 + off + lane]);
    float v2 = __bfloat162float(P[(size_t)s2 * 256 + off + lane]);
    float v3 = __bfloat162float(P[(size_t)s3 * 256 + off + lane]);
    a0 += fmaxf(v0 + bv, 0.f);
    a1 += fmaxf(v1 + bv, 0.f);
    a2 += fmaxf(v2 + bv, 0.f);
    a3 += fmaxf(v3 + bv, 0.f);
  }
  for (; p < end; ++p) {
    int s = packed[p];
    a0 += fmaxf(__bfloat162float(P[(size_t)s * 256 + off + lane]) + bv, 0.f);
  }
  return (a0 + a1) + (a2 + a3);
}

__global__ __launch_bounds__(256) void k_edge(const bf16* __restrict__ P,
                                              const int* __restrict__ rs,
                                              const int* __restrict__ packed,
                                              const float* __restrict__ W2,  // [2][64][32]
                                              const float* __restrict__ b2,  // [2][32]
                                              float* __restrict__ msg, int n) {
  __shared__ float s_w2[2 * 64 * 32];
  __shared__ float s_b2[64];
  __shared__ float s_acc[4][2][64];
  int t = threadIdx.x;
  for (int i = t; i < 4096; i += 256) s_w2[i] = W2[i];
  if (t < 64) s_b2[t] = b2[t];
  __syncthreads();
  int w = t >> 6, lane = t & 63;
  int ngroups = (n + 3) >> 2;
  for (int g = blockIdx.x; g < ngroups; g += gridDim.x) {
    int node = g * 4 + w;
    float m0 = 0.f, m1 = 0.f;
    int c0 = 0, c1 = 0;
    if (node < n) {
      const bf16* Pb = P + (size_t)node * 256 + 128;
      float b0v = __bfloat162float(Pb[lane]);
      float b1v = __bfloat162float(Pb[64 + lane]);
      int r0 = rs[2 * node], r1 = rs[2 * node + 1], r2 = rs[2 * node + 2];
      c0 = r1 - r0; c1 = r2 - r1;
      m0 = seg_acc(P, packed, r0, r1, 0, lane, b0v);
      m1 = seg_acc(P, packed, r1, r2, 64, lane, b1v);
      m0 *= (c0 > 0) ? 1.f / (float)c0 : 0.f;
      m1 *= (c1 > 0) ? 1.f / (float)c1 : 0.f;
    }
    s_acc[w][0][lane] = m0;
    s_acc[w][1][lane] = m1;
    __syncthreads();
    if (node < n) {
      int e = lane >> 5, c = lane & 31;
      int cnte = e ? c1 : c0;
      float outv = (cnte > 0) ? s_b2[e * 32 + c] : 0.f;
      float sum = 0.f;
#pragma unroll 8
      for (int j = 0; j < 64; ++j)
        sum = fmaf(s_acc[w][e][j], s_w2[(e * 64 + j) * 32 + c], sum);
      msg[(size_t)node * 64 + lane] = outv + sum;
    }
    __syncthreads();
  }
}

// ---------------- launch ----------------

extern "C" void kernel_launch(void* const* d_in, const int* in_sizes, int n_in,
                              void* d_out, int out_size, void* d_ws, size_t ws_size,
                              hipStream_t stream) {
  const float* nf  = (const float*)d_in[0];
  const float* eW1 = (const float*)d_in[1];
  const float* eb1 = (const float*)d_in[2];
  const float* eW2 = (const float*)d_in[3];
  const float* eb2 = (const float*)d_in[4];
  const float* nW1 = (const float*)d_in[5];
  const float* nb1 = (const float*)d_in[6];
  const float* nW2 = (const float*)d_in[7];
  const float* nb2 = (const float*)d_in[8];
  const int* src = (const int*)d_in[9];
  const int* dst = (const int*)d_in[10];
  const int* et  = (const int*)d_in[11];
  const int N = in_sizes[0] / IN_DIM;
  const int E = in_sizes[9];
  const int M = 2 * N;  // etype-split segment count

  char* wp = (char*)d_ws;
  auto alloc = [&](size_t bytes) {
    char* p = wp; wp += (bytes + 255) & ~(size_t)255; return p;
  };
  int*   deg       = (int*)alloc((size_t)M * 4);
  int*   row_start = (int*)alloc((size_t)(M + 1) * 4);
  int*   cursor    = (int*)alloc((size_t)M * 4);
  int*   tmp       = (int*)alloc((size_t)M * 4);
  int*   bsum      = (int*)alloc((size_t)256 * 4);
  int*   packed    = (int*)alloc((size_t)E * 4);
  float* Wcat      = (float*)alloc((size_t)3 * 128 * 256 * 4);
  float* bcat      = (float*)alloc((size_t)3 * 256 * 4);
  bf16*  P         = (bf16*)alloc((size_t)N * 256 * 2);
  float* msg       = (float*)alloc((size_t)N * 64 * 4);
  float* U         = (float*)alloc((size_t)N * 64 * 4);
  float* hbuf      = (float*)alloc((size_t)N * 128 * 4);

  int nbA = (M + 1023) / 1024;  // 98 for N=50000; must be <= 256
  hipMemsetAsync(deg, 0, (size_t)M * 4, stream);
  k_count<<<(E + 255) / 256, 256, 0, stream>>>(dst, et, deg, E);
  k_scanA<<<nbA, 256, 0, stream>>>(deg, tmp, bsum, M);
  k_scanB<<<1, 256, 0, stream>>>(bsum, nbA);
  k_scanC<<<(M + 255) / 256, 256, 0, stream>>>(tmp, bsum, row_start, cursor, M, E);
  k_fill<<<(E + 255) / 256, 256, 0, stream>>>(src, dst, et, cursor, packed, E);
  k_prep<<<(3 * 128 * 256 + 255) / 256, 256, 0, stream>>>(eW1, eb1, Wcat, bcat);

  int gm = (N + 63) / 64;
  const float* h = nf;
  for (int l = 0; l < 3; ++l) {
    // P = h @ Wcat[l] + bcat[l]  -> bf16 [N,256]
    k_gemm<128, 256, false, true, false><<<dim3(gm, 4), 256, 0, stream>>>(
        h, nullptr, Wcat + l * 128 * 256, bcat + l * 256, P, N);
    // per-node message accumulation + mean + @W2 + b2
    k_edge<<<2048, 256, 0, stream>>>(
        P, row_start, packed, eW2 + l * 2 * 64 * 32, eb2 + l * 2 * 32, msg, N);
    // U = relu([msg | h] @ nW1[l] + nb1[l])
    k_gemm<192, 64, true, false, true><<<dim3(gm, 1), 256, 0, stream>>>(
        msg, h, nW1 + l * 192 * 64, nb1 + l * 64, U, N);
    // h' = U @ nW2[l] + nb2[l]
    float* hout = (l == 2) ? (float*)d_out : hbuf;
    k_gemm<64, 128, false, false, false><<<dim3(gm, 2), 256, 0, stream>>>(
        U, nullptr, nW2 + l * 64 * 128, nb2 + l * 128, hout, N);
    h = hbuf;
  }
}

// Round 3
// 380.530 us; speedup vs baseline: 2.0997x; 1.3694x over previous
//
#include <hip/hip_runtime.h>
#include <hip/hip_bf16.h>

#define IN_DIM 128

typedef __hip_bfloat16 bf16;
typedef __attribute__((ext_vector_type(8))) short frag8;   // 8 bf16 (4 VGPRs)
typedef __attribute__((ext_vector_type(4))) float f32x4;   // MFMA C/D

// ---------------- CSR build (etype-split: segment index = 2*dst + etype) ----------------

__global__ void k_count(const int* __restrict__ dst, const int* __restrict__ et,
                        int* __restrict__ deg, int E) {
  int i = blockIdx.x * 256 + threadIdx.x;
  if (i < E) atomicAdd(&deg[2 * dst[i] + et[i]], 1);
}

__global__ __launch_bounds__(256) void k_scanA(const int* __restrict__ deg,
                                               int* __restrict__ tmp,
                                               int* __restrict__ bsum, int M) {
  __shared__ int ts[256];
  int t = threadIdx.x;
  int base = blockIdx.x * 1024 + t * 4;
  int d[4];
#pragma unroll
  for (int i = 0; i < 4; ++i) d[i] = (base + i < M) ? deg[base + i] : 0;
  ts[t] = d[0] + d[1] + d[2] + d[3];
  __syncthreads();
  for (int dd = 1; dd < 256; dd <<= 1) {
    int v = (t >= dd) ? ts[t - dd] : 0;
    __syncthreads();
    ts[t] += v;
    __syncthreads();
  }
  int run = (t == 0) ? 0 : ts[t - 1];
#pragma unroll
  for (int i = 0; i < 4; ++i) {
    if (base + i < M) tmp[base + i] = run;
    run += d[i];
  }
  if (t == 255) bsum[blockIdx.x] = ts[255];
}

__global__ __launch_bounds__(256) void k_scanB(int* __restrict__ bsum, int nb) {
  __shared__ int s[256];
  int t = threadIdx.x;
  s[t] = (t < nb) ? bsum[t] : 0;
  __syncthreads();
  for (int dd = 1; dd < 256; dd <<= 1) {
    int v = (t >= dd) ? s[t - dd] : 0;
    __syncthreads();
    s[t] += v;
    __syncthreads();
  }
  if (t < nb) bsum[t] = (t == 0) ? 0 : s[t - 1];
}

__global__ void k_scanC(const int* __restrict__ tmp, const int* __restrict__ bsum,
                        int* __restrict__ row_start, int* __restrict__ cursor,
                        int M, int E) {
  int i = blockIdx.x * 256 + threadIdx.x;
  if (i < M) {
    int v = tmp[i] + bsum[i >> 10];
    row_start[i] = v;
    cursor[i] = v;
  }
  if (i == 0) row_start[M] = E;
}

__global__ void k_fill(const int* __restrict__ src, const int* __restrict__ dst,
                       const int* __restrict__ et, int* __restrict__ cursor,
                       int* __restrict__ packed, int E) {
  int i = blockIdx.x * 256 + threadIdx.x;
  if (i < E) {
    int pos = atomicAdd(&cursor[2 * dst[i] + et[i]], 1);
    packed[pos] = src[i];
  }
}

// ---------------- weight prep: transpose to [NCOL][K] bf16, pre-XOR-swizzled ----------------
// storage index (c, ks) holds logical k = ks ^ ((c&7)<<3)  (involution; 16B groups)

__global__ void k_prepW(const float* __restrict__ eW1, const float* __restrict__ eb1,
                        const float* __restrict__ nW1, const float* __restrict__ nW2,
                        bf16* __restrict__ WcatT, float* __restrict__ bcat,
                        bf16* __restrict__ nW1T, bf16* __restrict__ nW2T) {
  int idx = blockIdx.x * 256 + threadIdx.x;
  // WcatT: [3][256][128]
  if (idx < 3 * 256 * 128) {
    int l = idx / (256 * 128);
    int rr = idx % (256 * 128);
    int c = rr >> 7, ks = rr & 127;
    int k = ks ^ ((c & 7) << 3);
    int e = (c >> 6) & 1;
    int row = (c < 128) ? k : 128 + k;
    WcatT[idx] = __float2bfloat16(eW1[((l * 2 + e) * 256 + row) * 64 + (c & 63)]);
  }
  // nW1T: [3][64][192]
  int i1 = idx - 3 * 256 * 128;
  if (i1 >= 0 && i1 < 3 * 64 * 192) {
    int l = i1 / (64 * 192);
    int rr = i1 % (64 * 192);
    int c = rr / 192, ks = rr % 192;
    int k = ks ^ ((c & 7) << 3);
    nW1T[i1] = __float2bfloat16(nW1[(l * 192 + k) * 64 + c]);
  }
  // nW2T: [3][128][64]
  int i2 = i1 - 3 * 64 * 192;
  if (i2 >= 0 && i2 < 3 * 128 * 64) {
    int l = i2 / (128 * 64);
    int rr = i2 % (128 * 64);
    int c = rr >> 6, ks = rr & 63;
    int k = ks ^ ((c & 7) << 3);
    nW2T[i2] = __float2bfloat16(nW2[(l * 64 + k) * 128 + c]);
  }
  // bcat: [3][256] fp32 (b1 folded into B-columns)
  if (idx < 3 * 256) {
    int l = idx >> 8, c = idx & 255;
    float b = 0.f;
    if (c >= 128) {
      int e = (c >> 6) & 1;
      b = eb1[(l * 2 + e) * 64 + (c & 63)];
    }
    bcat[idx] = b;
  }
}

__global__ void k_cast(const float* __restrict__ in, bf16* __restrict__ out, int n4) {
  int i = blockIdx.x * 256 + threadIdx.x;
  if (i < n4) {
    float4 v = *reinterpret_cast<const float4*>(in + (size_t)i * 4);
    bf16* o = out + (size_t)i * 4;
    o[0] = __float2bfloat16(v.x);
    o[1] = __float2bfloat16(v.y);
    o[2] = __float2bfloat16(v.z);
    o[3] = __float2bfloat16(v.w);
  }
}

// ---------------- MFMA GEMM: out = [relu](A @ W + bias) ----------------
// A: bf16 [M,K] row-major (SPLIT_A: k<64 from A [M,64], k>=64 from A2 [M,128]).
// Wt: bf16 [NCOL][K] transposed, pre-swizzled. out: [M,NCOL] bf16 or fp32.
// Block: 256 thr = 4 waves (2x2), tile 64x64; wave 32x32 = 2x2 MFMA frags.

template <int K, int NCOL, bool RELU, bool OUT_BF16, bool SPLIT_A>
__global__ __launch_bounds__(256) void k_gemm_mfma(
    const bf16* __restrict__ A, const bf16* __restrict__ A2,
    const bf16* __restrict__ Wt, const float* __restrict__ bias,
    void* __restrict__ out, int M) {
  constexpr int PANEL_B = 64 * K * 2;
  __shared__ char lds_raw[PANEL_B];
  int t = threadIdx.x;
  int m0 = blockIdx.x * 64;
  int n0 = blockIdx.y * 64;
  {  // stage Wt rows n0..n0+63 (contiguous, swizzle pre-applied) -> linear LDS copy
    const uint4* g = reinterpret_cast<const uint4*>((const char*)Wt + (size_t)n0 * (K * 2));
    uint4* l = reinterpret_cast<uint4*>(lds_raw);
    for (int i = t; i < PANEL_B / 16; i += 256) l[i] = g[i];
  }
  __syncthreads();
  int lane = t & 63, w = t >> 6;
  int wm = w >> 1, wn = w & 1;
  int r = lane & 15, q = lane >> 4;
  f32x4 acc[2][2] = {};
  int row0 = m0 + wm * 32 + r;
  int row1 = row0 + 16;
  if (row0 >= M) row0 = M - 1;
  if (row1 >= M) row1 = M - 1;
#pragma unroll
  for (int kc = 0; kc < K; kc += 32) {
    int kk = kc + q * 8;
    frag8 a0, a1;
    if (SPLIT_A) {
      if (kc < 64) {
        a0 = *reinterpret_cast<const frag8*>(A + (size_t)row0 * 64 + kk);
        a1 = *reinterpret_cast<const frag8*>(A + (size_t)row1 * 64 + kk);
      } else {
        a0 = *reinterpret_cast<const frag8*>(A2 + (size_t)row0 * 128 + (kk - 64));
        a1 = *reinterpret_cast<const frag8*>(A2 + (size_t)row1 * 128 + (kk - 64));
      }
    } else {
      a0 = *reinterpret_cast<const frag8*>(A + (size_t)row0 * K + kk);
      a1 = *reinterpret_cast<const frag8*>(A + (size_t)row1 * K + kk);
    }
#pragma unroll
    for (int fn = 0; fn < 2; ++fn) {
      int c = wn * 32 + fn * 16 + r;
      int byte = c * (K * 2) + ((kk * 2) ^ ((c & 7) << 4));
      frag8 b = *reinterpret_cast<const frag8*>(lds_raw + byte);
      acc[0][fn] = __builtin_amdgcn_mfma_f32_16x16x32_bf16(a0, b, acc[0][fn], 0, 0, 0);
      acc[1][fn] = __builtin_amdgcn_mfma_f32_16x16x32_bf16(a1, b, acc[1][fn], 0, 0, 0);
    }
  }
  // epilogue: D row = q*4 + i, col = r  (within each 16x16 fragment)
#pragma unroll
  for (int fm = 0; fm < 2; ++fm) {
    int grow_base = m0 + wm * 32 + fm * 16 + q * 4;
#pragma unroll
    for (int fn = 0; fn < 2; ++fn) {
      int gcol = n0 + wn * 32 + fn * 16 + r;
      float bv = bias[gcol];
#pragma unroll
      for (int i = 0; i < 4; ++i) {
        int grow = grow_base + i;
        if (grow >= M) continue;
        float v = acc[fm][fn][i] + bv;
        if (RELU) v = fmaxf(v, 0.f);
        if (OUT_BF16) ((bf16*)out)[(size_t)grow * NCOL + gcol] = __float2bfloat16(v);
        else          ((float*)out)[(size_t)grow * NCOL + gcol] = v;
      }
    }
  }
}

// ---------------- edge phase ----------------
// P layout per node: [A0(64) | A1(64) | B0+b1(64) | B1+b1(64)] bf16.

__device__ __forceinline__ float seg_acc(const bf16* __restrict__ P,
                                         const int* __restrict__ packed,
                                         int beg, int end, int off, int lane,
                                         float bv) {
  float a0 = 0.f, a1 = 0.f, a2 = 0.f, a3 = 0.f;
  int p = beg;
  for (; p + 4 <= end; p += 4) {
    int s0 = packed[p], s1 = packed[p + 1], s2 = packed[p + 2], s3 = packed[p + 3];
    float v0 = __bfloat162float(P[(size_t)s0 * 256 + off + lane]);
    float v1 = __bfloat162float(P[(size_t)s1 * 256 + off + lane]);
    float v2 = __bfloat162float(P[(size_t)s2 * 256 + off + lane]);
    float v3 = __bfloat162float(P[(size_t)s3 * 256 + off + lane]);
    a0 += fmaxf(v0 + bv, 0.f);
    a1 += fmaxf(v1 + bv, 0.f);
    a2 += fmaxf(v2 + bv, 0.f);
    a3 += fmaxf(v3 + bv, 0.f);
  }
  for (; p < end; ++p) {
    int s = packed[p];
    a0 += fmaxf(__bfloat162float(P[(size_t)s * 256 + off + lane]) + bv, 0.f);
  }
  return (a0 + a1) + (a2 + a3);
}

__global__ __launch_bounds__(256) void k_edge(const bf16* __restrict__ P,
                                              const int* __restrict__ rs,
                                              const int* __restrict__ packed,
                                              const float* __restrict__ W2,  // [2][64][32]
                                              const float* __restrict__ b2,  // [2][32]
                                              bf16* __restrict__ msg, int n) {
  __shared__ float s_w2[2 * 64 * 32];
  __shared__ float s_b2[64];
  __shared__ float s_acc[4][2][64];
  int t = threadIdx.x;
  for (int i = t; i < 4096; i += 256) s_w2[i] = W2[i];
  if (t < 64) s_b2[t] = b2[t];
  __syncthreads();
  int w = t >> 6, lane = t & 63;
  int ngroups = (n + 3) >> 2;
  for (int g = blockIdx.x; g < ngroups; g += gridDim.x) {
    int node = g * 4 + w;
    float m0 = 0.f, m1 = 0.f;
    int c0 = 0, c1 = 0;
    if (node < n) {
      const bf16* Pb = P + (size_t)node * 256 + 128;
      float b0v = __bfloat162float(Pb[lane]);
      float b1v = __bfloat162float(Pb[64 + lane]);
      int r0 = rs[2 * node], r1 = rs[2 * node + 1], r2 = rs[2 * node + 2];
      c0 = r1 - r0; c1 = r2 - r1;
      m0 = seg_acc(P, packed, r0, r1, 0, lane, b0v);
      m1 = seg_acc(P, packed, r1, r2, 64, lane, b1v);
      m0 *= (c0 > 0) ? 1.f / (float)c0 : 0.f;
      m1 *= (c1 > 0) ? 1.f / (float)c1 : 0.f;
    }
    s_acc[w][0][lane] = m0;
    s_acc[w][1][lane] = m1;
    __syncthreads();
    if (node < n) {
      int e = lane >> 5, c = lane & 31;
      int cnte = e ? c1 : c0;
      float outv = (cnte > 0) ? s_b2[e * 32 + c] : 0.f;
      float sum = 0.f;
#pragma unroll 8
      for (int j = 0; j < 64; ++j)
        sum = fmaf(s_acc[w][e][j], s_w2[(e * 64 + j) * 32 + c], sum);
      msg[(size_t)node * 64 + lane] = __float2bfloat16(outv + sum);
    }
    __syncthreads();
  }
}

// ---------------- launch ----------------

extern "C" void kernel_launch(void* const* d_in, const int* in_sizes, int n_in,
                              void* d_out, int out_size, void* d_ws, size_t ws_size,
                              hipStream_t stream) {
  const float* nf  = (const float*)d_in[0];
  const float* eW1 = (const float*)d_in[1];
  const float* eb1 = (const float*)d_in[2];
  const float* eW2 = (const float*)d_in[3];
  const float* eb2 = (const float*)d_in[4];
  const float* nW1 = (const float*)d_in[5];
  const float* nb1 = (const float*)d_in[6];
  const float* nW2 = (const float*)d_in[7];
  const float* nb2 = (const float*)d_in[8];
  const int* src = (const int*)d_in[9];
  const int* dst = (const int*)d_in[10];
  const int* et  = (const int*)d_in[11];
  const int N = in_sizes[0] / IN_DIM;
  const int E = in_sizes[9];
  const int M = 2 * N;

  char* wp = (char*)d_ws;
  auto alloc = [&](size_t bytes) {
    char* p = wp; wp += (bytes + 255) & ~(size_t)255; return p;
  };
  int*   deg       = (int*)alloc((size_t)M * 4);
  int*   row_start = (int*)alloc((size_t)(M + 1) * 4);
  int*   cursor    = (int*)alloc((size_t)M * 4);
  int*   tmp       = (int*)alloc((size_t)M * 4);
  int*   bsum      = (int*)alloc((size_t)256 * 4);
  int*   packed    = (int*)alloc((size_t)E * 4);
  bf16*  WcatT     = (bf16*)alloc((size_t)3 * 256 * 128 * 2);
  float* bcat      = (float*)alloc((size_t)3 * 256 * 4);
  bf16*  nW1T      = (bf16*)alloc((size_t)3 * 64 * 192 * 2);
  bf16*  nW2T      = (bf16*)alloc((size_t)3 * 128 * 64 * 2);
  bf16*  P         = (bf16*)alloc((size_t)N * 256 * 2);
  bf16*  msg       = (bf16*)alloc((size_t)N * 64 * 2);
  bf16*  U         = (bf16*)alloc((size_t)N * 64 * 2);
  bf16*  hb0       = (bf16*)alloc((size_t)N * 128 * 2);
  bf16*  hb1       = (bf16*)alloc((size_t)N * 128 * 2);

  int nbA = (M + 1023) / 1024;
  hipMemsetAsync(deg, 0, (size_t)M * 4, stream);
  k_count<<<(E + 255) / 256, 256, 0, stream>>>(dst, et, deg, E);
  k_scanA<<<nbA, 256, 0, stream>>>(deg, tmp, bsum, M);
  k_scanB<<<1, 256, 0, stream>>>(bsum, nbA);
  k_scanC<<<(M + 255) / 256, 256, 0, stream>>>(tmp, bsum, row_start, cursor, M, E);
  k_fill<<<(E + 255) / 256, 256, 0, stream>>>(src, dst, et, cursor, packed, E);
  k_prepW<<<(3 * 256 * 128 + 3 * 64 * 192 + 3 * 128 * 64 + 255) / 256, 256, 0, stream>>>(
      eW1, eb1, nW1, nW2, WcatT, bcat, nW1T, nW2T);
  k_cast<<<((N * 128 / 4) + 255) / 256, 256, 0, stream>>>(nf, hb0, N * 128 / 4);

  int gm = (N + 63) / 64;
  bf16* hbs[2] = {hb0, hb1};
  for (int l = 0; l < 3; ++l) {
    const bf16* h = hbs[l & 1];
    bf16* hn = hbs[(l + 1) & 1];
    // P = h @ Wcat[l] + bcat[l]  -> bf16 [N,256]
    k_gemm_mfma<128, 256, false, true, false><<<dim3(gm, 4), 256, 0, stream>>>(
        h, nullptr, WcatT + (size_t)l * 256 * 128, bcat + l * 256, P, N);
    // per-node message mean + @W2 + b2 -> bf16 [N,64]
    k_edge<<<2048, 256, 0, stream>>>(
        P, row_start, packed, eW2 + l * 2 * 64 * 32, eb2 + l * 2 * 32, msg, N);
    // U = relu([msg | h] @ nW1[l] + nb1[l]) -> bf16 [N,64]
    k_gemm_mfma<192, 64, true, true, true><<<dim3(gm, 1), 256, 0, stream>>>(
        msg, h, nW1T + (size_t)l * 64 * 192, nb1 + l * 64, U, N);
    // h' = U @ nW2[l] + nb2[l]
    if (l == 2) {
      k_gemm_mfma<64, 128, false, false, false><<<dim3(gm, 2), 256, 0, stream>>>(
          U, nullptr, nW2T + (size_t)l * 128 * 64, nb2 + l * 128, d_out, N);
    } else {
      k_gemm_mfma<64, 128, false, true, false><<<dim3(gm, 2), 256, 0, stream>>>(
          U, nullptr, nW2T + (size_t)l * 128 * 64, nb2 + l * 128, hn, N);
    }
  }
}